// Round 4
// baseline (493.282 us; speedup 1.0000x reference)
//
#include <hip/hip_runtime.h>

#define EPS_F 0.1f
#define A_F 100.0f
#define NUMNEG_F 10.0f
#define EXP_EPS 1.1051709f   // e^0.1; gate: dist<EPS  <=>  (-inner + s) < e^EPS
#define BATCH 8

__global__ __launch_bounds__(256) void grp_edge_kernel(
    const float* __restrict__ x,
    const int* __restrict__ u_idx,
    const int* __restrict__ v_idx,
    float* __restrict__ out,   // out[0]=energy, out+1 = grad (N*64)
    int E)
{
    const int lane = threadIdx.x & 63;
    const int wave = (blockIdx.x * blockDim.x + threadIdx.x) >> 6;
    const int nwaves = (gridDim.x * blockDim.x) >> 6;
    const float sign = (lane == 0) ? -1.0f : 1.0f;  // Minkowski J
    float* __restrict__ grad = out + 1;

    float eacc = 0.0f;

    // each wave takes contiguous 64-edge chunks; indices loaded coalesced once
    for (int base = wave * 64; base < E; base += nwaves * 64) {
        const int n = min(64, E - base);
        int myu = 0, myv = 0;
        if (lane < n) { myu = u_idx[base + lane]; myv = v_idx[base + lane]; }

        for (int i = 0; i < n; i += BATCH) {
            const int bn = min(BATCH, n - i);
            int us[BATCH], vs[BATCH];
            float xu[BATCH], xv[BATCH], p[BATCH];

            // broadcast edge indices to SGPRs, issue all gathers back-to-back (MLP)
            #pragma unroll
            for (int k = 0; k < BATCH; k++) {
                if (k < bn) {
                    us[k] = __builtin_amdgcn_readlane(myu, i + k);
                    vs[k] = __builtin_amdgcn_readlane(myv, i + k);
                    xu[k] = x[(size_t)us[k] * 64 + lane];
                    xv[k] = x[(size_t)vs[k] * 64 + lane];
                }
            }

            #pragma unroll
            for (int k = 0; k < BATCH; k++)
                p[k] = (k < bn) ? xu[k] * xv[k] * sign : 0.0f;

            // 8 independent butterfly chains interleaved level-by-level
            #pragma unroll
            for (int off = 32; off >= 1; off >>= 1) {
                #pragma unroll
                for (int k = 0; k < BATCH; k++)
                    p[k] += __shfl_xor(p[k], off, 64);
            }

            #pragma unroll
            for (int k = 0; k < BATCH; k++) {
                if (k < bn) {
                    const float inner = fminf(p[k], -1.0f - 1e-7f);
                    const float s = sqrtf(inner * inner - 1.0f);
                    const float t = -inner + s;            // dist = log(t)
                    if (t < EXP_EPS) {                     // wave-uniform branch
                        const float dist = __logf(t);
                        const float delta = EPS_F - dist;
                        eacc += delta * delta;             // wave-uniform value
                        const float factor = -(A_F / NUMNEG_F) * delta / (s + 1e-9f);
                        unsafeAtomicAdd(&grad[(size_t)us[k] * 64 + lane], factor * xv[k] * sign);
                        unsafeAtomicAdd(&grad[(size_t)vs[k] * 64 + lane], factor * xu[k] * sign);
                    }
                }
            }
        }
    }

    // eacc is identical on all lanes (wave-uniform); add once
    if (lane == 0 && eacc != 0.0f)
        unsafeAtomicAdd(&out[0], eacc * (0.5f * A_F / NUMNEG_F));
}

extern "C" void kernel_launch(void* const* d_in, const int* in_sizes, int n_in,
                              void* d_out, int out_size, void* d_ws, size_t ws_size,
                              hipStream_t stream) {
    const float* x     = (const float*)d_in[0];
    const int*   u_idx = (const int*)d_in[1];
    const int*   v_idx = (const int*)d_in[2];
    float* out = (float*)d_out;
    const int E = in_sizes[1];

    hipMemsetAsync(d_out, 0, (size_t)out_size * sizeof(float), stream);

    // 4096 blocks x 4 waves = 16384 waves; 15625 chunks of 64 edges
    grp_edge_kernel<<<4096, 256, 0, stream>>>(x, u_idx, v_idx, out, E);
}

// Round 5
// 390.900 us; speedup vs baseline: 1.2619x; 1.2619x over previous
//
#include <hip/hip_runtime.h>

#define EPS_F 0.1f
#define A_F 100.0f
#define NUMNEG_F 10.0f
#define EXP_EPS 1.1051709f   // e^0.1; gate: dist<EPS  <=>  (-inner + s) < e^EPS
#define BATCH 8
#define NBLOCKS 4096

__global__ __launch_bounds__(256) void grp_edge_kernel(
    const float* __restrict__ x,
    const int* __restrict__ u_idx,
    const int* __restrict__ v_idx,
    float* __restrict__ out,          // out[0]=energy, out+1 = grad (N*64)
    float* __restrict__ block_energy, // ws: one float per block
    int E)
{
    const int lane = threadIdx.x & 63;
    const int wib  = threadIdx.x >> 6;                  // wave in block
    const int wave = (blockIdx.x * blockDim.x + threadIdx.x) >> 6;
    const int nwaves = (gridDim.x * blockDim.x) >> 6;
    const float sign = (lane == 0) ? -1.0f : 1.0f;      // Minkowski J
    float* __restrict__ grad = out + 1;

    float eacc = 0.0f;

    for (int base = wave * 64; base < E; base += nwaves * 64) {
        const int n = min(64, E - base);
        int myu = 0, myv = 0;
        if (lane < n) { myu = u_idx[base + lane]; myv = v_idx[base + lane]; }

        for (int i = 0; i < n; i += BATCH) {
            const int bn = min(BATCH, n - i);
            int us[BATCH], vs[BATCH];
            float xu[BATCH], xv[BATCH], p[BATCH];

            #pragma unroll
            for (int k = 0; k < BATCH; k++) {
                if (k < bn) {
                    us[k] = __builtin_amdgcn_readlane(myu, i + k);
                    vs[k] = __builtin_amdgcn_readlane(myv, i + k);
                    xu[k] = x[(size_t)us[k] * 64 + lane];
                    xv[k] = x[(size_t)vs[k] * 64 + lane];
                }
            }

            #pragma unroll
            for (int k = 0; k < BATCH; k++)
                p[k] = (k < bn) ? xu[k] * xv[k] * sign : 0.0f;

            #pragma unroll
            for (int off = 32; off >= 1; off >>= 1) {
                #pragma unroll
                for (int k = 0; k < BATCH; k++)
                    p[k] += __shfl_xor(p[k], off, 64);
            }

            #pragma unroll
            for (int k = 0; k < BATCH; k++) {
                if (k < bn) {
                    const float inner = fminf(p[k], -1.0f - 1e-7f);
                    const float s = sqrtf(inner * inner - 1.0f);
                    const float t = -inner + s;            // dist = log(t)
                    if (t < EXP_EPS) {                     // wave-uniform branch
                        const float dist = __logf(t);
                        const float delta = EPS_F - dist;
                        eacc += delta * delta;             // wave-uniform value
                        const float factor = -(A_F / NUMNEG_F) * delta / (s + 1e-9f);
                        unsafeAtomicAdd(&grad[(size_t)us[k] * 64 + lane], factor * xv[k] * sign);
                        unsafeAtomicAdd(&grad[(size_t)vs[k] * 64 + lane], factor * xu[k] * sign);
                    }
                }
            }
        }
    }

    // energy: NO global atomics. eacc is wave-uniform; block-reduce in LDS,
    // one plain store per block into ws.
    __shared__ float se[4];
    if (lane == 0) se[wib] = eacc;
    __syncthreads();
    if (threadIdx.x == 0)
        block_energy[blockIdx.x] = se[0] + se[1] + se[2] + se[3];
}

__global__ __launch_bounds__(256) void energy_reduce_kernel(
    const float* __restrict__ block_energy, float* __restrict__ out, int n)
{
    const int lane = threadIdx.x & 63;
    const int wib  = threadIdx.x >> 6;
    float s = 0.0f;
    for (int i = threadIdx.x; i < n; i += 256) s += block_energy[i];
    #pragma unroll
    for (int off = 32; off >= 1; off >>= 1) s += __shfl_xor(s, off, 64);
    __shared__ float se[4];
    if (lane == 0) se[wib] = s;
    __syncthreads();
    if (threadIdx.x == 0)
        out[0] = (se[0] + se[1] + se[2] + se[3]) * (0.5f * A_F / NUMNEG_F);
}

extern "C" void kernel_launch(void* const* d_in, const int* in_sizes, int n_in,
                              void* d_out, int out_size, void* d_ws, size_t ws_size,
                              hipStream_t stream) {
    const float* x     = (const float*)d_in[0];
    const int*   u_idx = (const int*)d_in[1];
    const int*   v_idx = (const int*)d_in[2];
    float* out = (float*)d_out;
    float* block_energy = (float*)d_ws;   // NBLOCKS floats
    const int E = in_sizes[1];

    // zero grad (+energy slot; it is overwritten by the reduce kernel anyway)
    hipMemsetAsync(d_out, 0, (size_t)out_size * sizeof(float), stream);

    grp_edge_kernel<<<NBLOCKS, 256, 0, stream>>>(x, u_idx, v_idx, out, block_energy, E);
    energy_reduce_kernel<<<1, 256, 0, stream>>>(block_energy, out, NBLOCKS);
}

// Round 6
// 373.760 us; speedup vs baseline: 1.3198x; 1.0459x over previous
//
#include <hip/hip_runtime.h>

#define EPS_F 0.1f
#define A_F 100.0f
#define NUMNEG_F 10.0f
#define EXP_EPS 1.1051709f   // e^0.1; gate: dist<EPS  <=>  (-inner + s) < e^EPS
#define BATCH 8
#define NBLOCKS 4096

__device__ __forceinline__ void edge_tail(
    float p, float xu, float xv, float sign, int u, int v, int lane,
    float* __restrict__ grad, float& eacc)
{
    const float inner = fminf(p, -1.0f - 1e-7f);
    const float s = sqrtf(inner * inner - 1.0f);
    const float t = -inner + s;                 // dist = log(t)
    if (t < EXP_EPS) {                          // wave-uniform branch
        const float dist = __logf(t);
        const float delta = EPS_F - dist;
        eacc += delta * delta;                  // wave-uniform value
        const float factor = -(A_F / NUMNEG_F) * delta / (s + 1e-9f);
        unsafeAtomicAdd(&grad[(size_t)u * 64 + lane], factor * xv * sign);
        unsafeAtomicAdd(&grad[(size_t)v * 64 + lane], factor * xu * sign);
    }
}

__global__ __launch_bounds__(256) void grp_edge_kernel(
    const float* __restrict__ x,
    const int* __restrict__ u_idx,
    const int* __restrict__ v_idx,
    float* __restrict__ out,          // out[0]=energy, out+1 = grad (N*64)
    float* __restrict__ block_energy, // ws: one float per block
    int E)
{
    const int lane = threadIdx.x & 63;
    const int wib  = threadIdx.x >> 6;
    const int wave = (blockIdx.x * blockDim.x + threadIdx.x) >> 6;
    const int nwaves = (gridDim.x * blockDim.x) >> 6;
    const float sign = (lane == 0) ? -1.0f : 1.0f;  // Minkowski J
    float* __restrict__ grad = out + 1;

    float eacc = 0.0f;

    for (int base = wave * 64; base < E; base += nwaves * 64) {
        const int n = min(64, E - base);
        int myu = 0, myv = 0;
        if (lane < n) { myu = u_idx[base + lane]; myv = v_idx[base + lane]; }

        if (n == 64) {
            // ---- pipelined path: prefetch batch b+1's gathers BEFORE batch b's
            // atomics so the in-order vmcnt retire never waits on atomic RTT ----
            int   us[2][BATCH], vs[2][BATCH];
            float xu[2][BATCH], xv[2][BATCH];

            #pragma unroll
            for (int k = 0; k < BATCH; k++) {              // prologue: batch 0
                us[0][k] = __builtin_amdgcn_readlane(myu, k);
                vs[0][k] = __builtin_amdgcn_readlane(myv, k);
                xu[0][k] = x[(size_t)us[0][k] * 64 + lane];
                xv[0][k] = x[(size_t)vs[0][k] * 64 + lane];
            }

            #pragma unroll
            for (int b = 0; b < 64 / BATCH; b++) {
                const int cur = b & 1, nxt = cur ^ 1;
                if (b < 64 / BATCH - 1) {                  // prefetch batch b+1
                    #pragma unroll
                    for (int k = 0; k < BATCH; k++) {
                        const int e = (b + 1) * BATCH + k;
                        us[nxt][k] = __builtin_amdgcn_readlane(myu, e);
                        vs[nxt][k] = __builtin_amdgcn_readlane(myv, e);
                        xu[nxt][k] = x[(size_t)us[nxt][k] * 64 + lane];
                        xv[nxt][k] = x[(size_t)vs[nxt][k] * 64 + lane];
                    }
                }
                float p[BATCH];
                #pragma unroll
                for (int k = 0; k < BATCH; k++)
                    p[k] = xu[cur][k] * xv[cur][k] * sign;
                #pragma unroll
                for (int off = 32; off >= 1; off >>= 1) {
                    #pragma unroll
                    for (int k = 0; k < BATCH; k++)
                        p[k] += __shfl_xor(p[k], off, 64);
                }
                #pragma unroll
                for (int k = 0; k < BATCH; k++)            // atomics AFTER prefetch
                    edge_tail(p[k], xu[cur][k], xv[cur][k], sign,
                              us[cur][k], vs[cur][k], lane, grad, eacc);
            }
        } else {
            // ---- guarded tail path (rarely taken) ----
            for (int i = 0; i < n; i += BATCH) {
                const int bn = min(BATCH, n - i);
                int us[BATCH], vs[BATCH];
                float xu[BATCH], xv[BATCH], p[BATCH];
                #pragma unroll
                for (int k = 0; k < BATCH; k++) {
                    if (k < bn) {
                        us[k] = __builtin_amdgcn_readlane(myu, i + k);
                        vs[k] = __builtin_amdgcn_readlane(myv, i + k);
                        xu[k] = x[(size_t)us[k] * 64 + lane];
                        xv[k] = x[(size_t)vs[k] * 64 + lane];
                    }
                }
                #pragma unroll
                for (int k = 0; k < BATCH; k++)
                    p[k] = (k < bn) ? xu[k] * xv[k] * sign : 0.0f;
                #pragma unroll
                for (int off = 32; off >= 1; off >>= 1) {
                    #pragma unroll
                    for (int k = 0; k < BATCH; k++)
                        p[k] += __shfl_xor(p[k], off, 64);
                }
                #pragma unroll
                for (int k = 0; k < BATCH; k++)
                    if (k < bn)
                        edge_tail(p[k], xu[k], xv[k], sign, us[k], vs[k],
                                  lane, grad, eacc);
            }
        }
    }

    // energy: no global atomics; eacc is wave-uniform
    __shared__ float se[4];
    if (lane == 0) se[wib] = eacc;
    __syncthreads();
    if (threadIdx.x == 0)
        block_energy[blockIdx.x] = se[0] + se[1] + se[2] + se[3];
}

__global__ __launch_bounds__(256) void energy_reduce_kernel(
    const float* __restrict__ block_energy, float* __restrict__ out, int n)
{
    const int lane = threadIdx.x & 63;
    const int wib  = threadIdx.x >> 6;
    float s = 0.0f;
    for (int i = threadIdx.x; i < n; i += 256) s += block_energy[i];
    #pragma unroll
    for (int off = 32; off >= 1; off >>= 1) s += __shfl_xor(s, off, 64);
    __shared__ float se[4];
    if (lane == 0) se[wib] = s;
    __syncthreads();
    if (threadIdx.x == 0)
        out[0] = (se[0] + se[1] + se[2] + se[3]) * (0.5f * A_F / NUMNEG_F);
}

extern "C" void kernel_launch(void* const* d_in, const int* in_sizes, int n_in,
                              void* d_out, int out_size, void* d_ws, size_t ws_size,
                              hipStream_t stream) {
    const float* x     = (const float*)d_in[0];
    const int*   u_idx = (const int*)d_in[1];
    const int*   v_idx = (const int*)d_in[2];
    float* out = (float*)d_out;
    float* block_energy = (float*)d_ws;   // NBLOCKS floats
    const int E = in_sizes[1];

    hipMemsetAsync(d_out, 0, (size_t)out_size * sizeof(float), stream);

    grp_edge_kernel<<<NBLOCKS, 256, 0, stream>>>(x, u_idx, v_idx, out, block_energy, E);
    energy_reduce_kernel<<<1, 256, 0, stream>>>(block_energy, out, NBLOCKS);
}